// Round 10
// baseline (22.770 us; speedup 1.0000x reference)
//
#include <hip/hip_runtime.h>
#include <math.h>

#define NPAR 130048
#define EPSF 1e-5f

typedef _Float16 hfp;
typedef _Float16 h2x __attribute__((ext_vector_type(2)));
typedef _Float16 h4x __attribute__((ext_vector_type(4)));
typedef float    f4x __attribute__((ext_vector_type(4)));

// ---- strides ----
#define BSTR  164      // beta row stride (f32)
#define VSTR2 172      // vposT row stride (halves)
#define ATSTR 172      // att row stride (halves)
#define WOSTR 76       // Wo / L1 / O / H1 row stride (halves)
#define L2STRH 108     // L2 / R row stride (halves)

// ---- ws layout (float offsets) — produced by k_pre, read directly (L2) by k_main ----
#define OFF_VPOST 0        // f16 [64][172]
#define OFF_WO    5504     // f16 [64][76]
#define OFF_L1    7936     // f16 [96][76]
#define OFF_L2    11584    // f16 [64][108]
#define OFF_BETA  15040    // f32 [4][164]
#define OFF_SM    15696    // f32 smalls
#define SM_CT   0
#define SM_BO   64
#define SM_B1   128
#define SM_B2   224
#define SM_LN1W 288
#define SM_LN1B 352
#define SM_LN2W 416
#define SM_LN2B 480
#define SM_ALPH 544
#define SM_GAM  548
#define SM_BOCT 576        // bo + ct precombined

// ---- per-block (one wave) LDS layout (float offsets) ----
#define L_W    0           // f32 [4][148]
#define L_ATT  592         // f16 [16][172] = 1376 floats
#define L_INVS 1968        // f32 [16]
#define L_O    1984        // f16 [16][76] = 608
#define L_H1   2592        // f16 [16][76] = 608
#define L_R    3200        // f16 [16][108] = 864
#define L_PRE  4064        // f32 [4][68] = 272
#define LDS_FLOATS 4352    // 17,408 B

// wave-local fence: all LDS deps are intra-wave.
#define WAVE_SYNC() asm volatile("s_waitcnt lgkmcnt(0)" ::: "memory")

template<int C>
__device__ __forceinline__ float dppf(float x) {
    return __int_as_float(__builtin_amdgcn_update_dpp(0, __float_as_int(x), C, 0xf, 0xf, false));
}
__device__ __forceinline__ float rowsum16(float x) {
    x += dppf<0x128>(x); x += dppf<0x124>(x); x += dppf<0x122>(x); x += dppf<0x121>(x);
    return x;
}
__device__ __forceinline__ float rowmax16(float x) {
    x = fmaxf(x, dppf<0x128>(x)); x = fmaxf(x, dppf<0x124>(x));
    x = fmaxf(x, dppf<0x122>(x)); x = fmaxf(x, dppf<0x121>(x));
    return x;
}
__device__ __forceinline__ unsigned packh2(float a, float b) {
    union { h2x h; unsigned u; } cv;
    cv.h.x = (hfp)a; cv.h.y = (hfp)b;
    return cv.u;
}

// ===================== k_pre: identical to R9 =====================
__global__ __launch_bounds__(64) void k_pre(const float* __restrict__ pe,
                                            const float* __restrict__ ct,
                                            const float* __restrict__ W,
                                            const float* __restrict__ bq,
                                            const float* __restrict__ Wo,
                                            const float* __restrict__ bo,
                                            const float* __restrict__ L1w,
                                            const float* __restrict__ b1,
                                            const float* __restrict__ L2w,
                                            const float* __restrict__ b2,
                                            const float* __restrict__ ln1w,
                                            const float* __restrict__ ln1b,
                                            const float* __restrict__ ln2w,
                                            const float* __restrict__ ln2b,
                                            float* __restrict__ ws)
{
    const int j = blockIdx.x;
    const int o = threadIdx.x;
    hfp* wsh = (hfp*)ws;

    if (j < 145) {
        const float4* wq4 = (const float4*)(W + o*64);
        const float4* wk4 = (const float4*)(W + (64 + o)*64);
        const float4* wv4 = (const float4*)(W + (128 + o)*64);
        const float4* p4  = (const float4*)(pe + j*64);
        float sk = bq[64 + o], sv = bq[128 + o], sq = bq[o];
        #pragma unroll
        for (int e = 0; e < 16; ++e) {
            float4 k4 = wk4[e], v4 = wv4[e], q4 = wq4[e], pp = p4[e];
            float4 cc = ((const float4*)ct)[e];
            sk += k4.x*pp.x + k4.y*pp.y + k4.z*pp.z + k4.w*pp.w;
            sv += v4.x*pp.x + v4.y*pp.y + v4.z*pp.z + v4.w*pp.w;
            sq += q4.x*cc.x + q4.y*cc.y + q4.z*cc.z + q4.w*cc.w;
        }
        wsh[o*VSTR2 + j] = (hfp)sv;
        float r = sq * sk;
        #pragma unroll
        for (int off = 1; off < 16; off <<= 1) r += __shfl_xor(r, off);
        if ((o & 15) == 0) ws[OFF_BETA + (o >> 4)*BSTR + j] = r;
    } else if (j == 145) {
        const float4* wq4 = (const float4*)(W + o*64);
        const float4* wk4 = (const float4*)(W + (64 + o)*64);
        const float4* wv4 = (const float4*)(W + (128 + o)*64);
        float sq = bq[o], sk = bq[64 + o], sv = bq[128 + o], suk = 0.f, suv = 0.f;
        #pragma unroll
        for (int e = 0; e < 16; ++e) {
            float4 k4 = wk4[e], v4 = wv4[e], q4 = wq4[e];
            float4 cc = ((const float4*)ct)[e];
            sq += q4.x*cc.x + q4.y*cc.y + q4.z*cc.z + q4.w*cc.w;
            sk += k4.x*cc.x + k4.y*cc.y + k4.z*cc.z + k4.w*cc.w;
            sv += v4.x*cc.x + v4.y*cc.y + v4.z*cc.z + v4.w*cc.w;
            suk += k4.x + k4.y + k4.z + k4.w;
            suv += v4.x + v4.y + v4.z + v4.w;
        }
        wsh[o*VSTR2 + 156] = (hfp)sv;     // vcls
        wsh[o*VSTR2 + 157] = (hfp)suv;    // uv
        #pragma unroll
        for (int c = 145; c < 156; ++c) wsh[o*VSTR2 + c] = (hfp)0.f;
        wsh[o*VSTR2 + 158] = (hfp)0.f;
        wsh[o*VSTR2 + 159] = (hfp)0.f;
        float a = sq * suk, g = sq * sk;
        #pragma unroll
        for (int off = 1; off < 16; off <<= 1) {
            a += __shfl_xor(a, off);
            g += __shfl_xor(g, off);
        }
        if ((o & 15) == 0) {
            ws[OFF_SM + SM_ALPH + (o >> 4)] = a;
            ws[OFF_SM + SM_GAM  + (o >> 4)] = g;
        }
    } else if (j == 146) {
        ws[OFF_SM + SM_CT   + o] = ct[o];
        ws[OFF_SM + SM_BO   + o] = bo[o];
        ws[OFF_SM + SM_BOCT + o] = bo[o] + ct[o];
        ws[OFF_SM + SM_B2   + o] = b2[o];
        ws[OFF_SM + SM_LN1W + o] = ln1w[o];
        ws[OFF_SM + SM_LN1B + o] = ln1b[o];
        ws[OFF_SM + SM_LN2W + o] = ln2w[o];
        ws[OFF_SM + SM_LN2B + o] = ln2b[o];
        ws[OFF_SM + SM_B1   + o] = b1[o];
        if (o < 32) ws[OFF_SM + SM_B1 + 64 + o] = b1[64 + o];
    } else if (j == 147) {
        for (int idx = o; idx < 4096; idx += 64)
            wsh[OFF_WO*2 + (idx >> 6)*WOSTR + (idx & 63)] = (hfp)Wo[idx];
    } else if (j == 148) {
        for (int idx = o; idx < 6144; idx += 64)
            wsh[OFF_L1*2 + (idx >> 6)*WOSTR + (idx & 63)] = (hfp)L1w[idx];
    } else {
        for (int idx = o; idx < 6144; idx += 64) {
            int r = idx / 96, c = idx - r*96;
            wsh[OFF_L2*2 + r*L2STRH + c] = (hfp)L2w[idx];
        }
    }
}

// ===================== k_main: one independent wave per 4 sequences, no barriers =====================
template<int L>
__device__ __forceinline__ void run4(const float* __restrict__ x,
                                     const float* __restrict__ ws,
                                     float* __restrict__ lds,
                                     float* __restrict__ out,
                                     int b, int k0, int start, int kno, int kgo)
{
    const int lane = threadIdx.x;
    const int e16  = lane & 15;
    const int g4   = (lane >> 4) * 4;
    const int c0   = e16 * 4;
    const int hs   = lane >> 4;          // head for softmax/maxbeta phases
    const hfp* wsh  = (const hfp*)ws;
    const hfp* ldsh = (const hfp*)lds;

    // ---------- phase 1: stage 4 seqs' params; wmax; maxbeta ----------
    constexpr int LC = L / 4;            // f4 chunks per row (18 or 36)
    float wm = 0.f;
    {
        const f4x* src = (const f4x*)(x + (size_t)b*NPAR + start + (size_t)k0*L);
        #pragma unroll
        for (int c = lane; c < L; c += 64) {     // L f4 chunks total (4 rows)
            f4x v = src[c];
            const int m = c / LC, col4 = c - m*LC;
            *(f4x*)(lds + L_W + m*148 + col4*4) = v;
            wm = fmaxf(wm, fmaxf(fmaxf(fabsf(v.x), fabsf(v.y)), fmaxf(fabsf(v.z), fabsf(v.w))));
        }
        if (lane < 4) {
            float bwv = x[(size_t)b*NPAR + start + (size_t)kno*L + k0 + lane];
            lds[L_W + lane*148 + L] = bwv;
            wm = fmaxf(wm, fabsf(bwv));
        }
        #pragma unroll
        for (int off = 1; off < 64; off <<= 1) wm = fmaxf(wm, __shfl_xor(wm, off));
    }
    float mb = -1e30f;
    #pragma unroll
    for (int t = 0; t < 10; ++t) {
        const int j = e16 + 16*t;
        if (j < 145) mb = fmaxf(mb, ws[OFF_BETA + hs*BSTR + j]);
    }
    mb = rowmax16(mb);
    const float alpha = ws[OFF_SM + SM_ALPH + hs];
    const float gam   = ws[OFF_SM + SM_GAM  + hs];
    WAVE_SYNC();

    // ---------- phase 2: softmax — row r = h*4+m = lane>>2, segment q = lane&3 ----------
    {
        const int r = lane >> 2;
        const int m = r & 3, q = lane & 3;
        const float M = fmaxf(0.25f*(fabsf(alpha)*wm + mb), 0.25f*gam);
        unsigned* arow32 = (unsigned*)(lds + L_ATT) + r*(ATSTR/2);
        const float* wr = lds + L_W + m*148;
        const float* br = ws + OFF_BETA + hs*BSTR;
        float S = 0.f, WS = 0.f;
        #pragma unroll
        for (int t = 0; t < 10; ++t) {
            const int j0 = 16*t + 4*q;
            if (j0 + 3 < L) {
                f4x wv = *(const f4x*)(wr + j0);
                f4x bv = *(const f4x*)(br + j0);
                float p0 = __expf(fmaf(alpha, wv.x, bv.x)*0.25f - M);
                float p1 = __expf(fmaf(alpha, wv.y, bv.y)*0.25f - M);
                float p2 = __expf(fmaf(alpha, wv.z, bv.z)*0.25f - M);
                float p3 = __expf(fmaf(alpha, wv.w, bv.w)*0.25f - M);
                S  += (p0 + p1) + (p2 + p3);
                WS += (p0*wv.x + p1*wv.y) + (p2*wv.z + p3*wv.w);
                uint2 u; u.x = packh2(p0, p1); u.y = packh2(p2, p3);
                *(uint2*)(arow32 + (j0 >> 1)) = u;
            } else if (j0 <= L) {                   // chunk containing bias token
                float pv4[4] = {0.f, 0.f, 0.f, 0.f};
                #pragma unroll
                for (int ee = 0; ee < 4; ++ee) {
                    int j = j0 + ee;
                    if (j <= L) {
                        float w = (j < L) ? wr[j] : wr[L];
                        float p = __expf(fmaf(alpha, w, br[j])*0.25f - M);
                        S += p; WS += p*w; pv4[ee] = p;
                    }
                }
                uint2 u; u.x = packh2(pv4[0], pv4[1]); u.y = packh2(pv4[2], pv4[3]);
                *(uint2*)(arow32 + (j0 >> 1)) = u;
            } else if (j0 != 156) {
                uint2 z; z.x = 0u; z.y = 0u;
                *(uint2*)(arow32 + (j0 >> 1)) = z;
            }
        }
        S  += __shfl_xor(S, 1);  S  += __shfl_xor(S, 2);
        WS += __shfl_xor(WS, 1); WS += __shfl_xor(WS, 2);
        const float pc = __expf(0.25f*gam - M);
        S += pc;
        if (q == 0) {
            lds[L_INVS + r] = 1.f / S;
            arow32[78] = packh2(pc, WS);            // cols 156 (a0), 157 (wsum)
            arow32[79] = 0u;
        }
    }
    WAVE_SYNC();

    // ---------- phase 3: V-step — 4 head GEMMs [4x160]@[160x16] ----------
    {
        const hfp* atth = ldsh + L_ATT*2;
        f4x vacc[4];
        #pragma unroll
        for (int hh = 0; hh < 4; ++hh) {
            vacc[hh] = (f4x){0.f,0.f,0.f,0.f};
            #pragma unroll
            for (int kt = 0; kt < 10; ++kt) {
                h4x a  = *(const h4x*)(atth + (hh*4 + e16)*ATSTR + kt*16 + g4);
                h4x bf = *(const h4x*)(wsh + (16*hh + e16)*VSTR2 + kt*16 + g4);
                vacc[hh] = __builtin_amdgcn_mfma_f32_16x16x16f16(a, bf, vacc[hh], 0, 0, 0);
            }
        }
        if (lane < 16) {
            hfp* Oh = (hfp*)(lds + L_O);
            #pragma unroll
            for (int hh = 0; hh < 4; ++hh)
                #pragma unroll
                for (int rr = 0; rr < 4; ++rr)
                    Oh[rr*WOSTR + hh*16 + lane] = (hfp)(vacc[hh][rr] * lds[L_INVS + hh*4 + rr]);
        }
    }
    WAVE_SYNC();

    // ---------- phase 4: out-proj [4x64]@[64x64] ----------
    {
        const hfp* Oh = ldsh + L_O*2;
        h4x af[4];
        #pragma unroll
        for (int kt = 0; kt < 4; ++kt) af[kt] = *(const h4x*)(Oh + e16*WOSTR + kt*16 + g4);
        f4x pacc[4];
        #pragma unroll
        for (int tn = 0; tn < 4; ++tn) {
            pacc[tn] = (f4x){0.f,0.f,0.f,0.f};
            #pragma unroll
            for (int kt = 0; kt < 4; ++kt) {
                h4x bf = *(const h4x*)(wsh + OFF_WO*2 + (16*tn + e16)*WOSTR + kt*16 + g4);
                pacc[tn] = __builtin_amdgcn_mfma_f32_16x16x16f16(af[kt], bf, pacc[tn], 0, 0, 0);
            }
        }
        if (lane < 16) {
            #pragma unroll
            for (int tn = 0; tn < 4; ++tn) {
                const float boct = ws[OFF_SM + SM_BOCT + tn*16 + lane];
                #pragma unroll
                for (int rr = 0; rr < 4; ++rr)
                    lds[L_PRE + rr*68 + tn*16 + lane] = pacc[tn][rr] + boct;
            }
        }
    }
    WAVE_SYNC();

    // ---------- phase 5: LN1 (4 rows x 64 cols over 64 lanes) ----------
    const f4x ln1w4 = *(const f4x*)(ws + OFF_SM + SM_LN1W + c0);
    const f4x ln1b4 = *(const f4x*)(ws + OFF_SM + SM_LN1B + c0);
    {
        const int m = lane >> 4;
        f4x pv = *(const f4x*)(lds + L_PRE + m*68 + c0);
        float s = (pv.x + pv.y) + (pv.z + pv.w);
        float mu = rowsum16(s) * (1.f/64.f);
        f4x d; d.x = pv.x-mu; d.y = pv.y-mu; d.z = pv.z-mu; d.w = pv.w-mu;
        float v = (d.x*d.x + d.y*d.y) + (d.z*d.z + d.w*d.w);
        float rs = rsqrtf(rowsum16(v)*(1.f/64.f) + EPSF);
        h4x hv;
        hv.x = (hfp)(d.x*rs*ln1w4.x + ln1b4.x);
        hv.y = (hfp)(d.y*rs*ln1w4.y + ln1b4.y);
        hv.z = (hfp)(d.z*rs*ln1w4.z + ln1b4.z);
        hv.w = (hfp)(d.w*rs*ln1w4.w + ln1b4.w);
        *(h4x*)((hfp*)(lds + L_H1) + m*WOSTR + c0) = hv;
    }
    WAVE_SYNC();

    // ---------- phase 6: FF1 [4x64]@[64x96] + relu ----------
    {
        const hfp* H1h = ldsh + L_H1*2;
        h4x af[4];
        #pragma unroll
        for (int kt = 0; kt < 4; ++kt) af[kt] = *(const h4x*)(H1h + e16*WOSTR + kt*16 + g4);
        f4x racc[6];
        #pragma unroll
        for (int tt = 0; tt < 6; ++tt) {
            racc[tt] = (f4x){0.f,0.f,0.f,0.f};
            #pragma unroll
            for (int kt = 0; kt < 4; ++kt) {
                h4x bf = *(const h4x*)(wsh + OFF_L1*2 + (16*tt + e16)*WOSTR + kt*16 + g4);
                racc[tt] = __builtin_amdgcn_mfma_f32_16x16x16f16(af[kt], bf, racc[tt], 0, 0, 0);
            }
        }
        if (lane < 16) {
            hfp* Rh = (hfp*)(lds + L_R);
            #pragma unroll
            for (int tt = 0; tt < 6; ++tt) {
                const float bb = ws[OFF_SM + SM_B1 + tt*16 + lane];
                #pragma unroll
                for (int rr = 0; rr < 4; ++rr)
                    Rh[rr*L2STRH + tt*16 + lane] = (hfp)fmaxf(racc[tt][rr] + bb, 0.f);
            }
        }
    }
    WAVE_SYNC();

    // ---------- phase 7: FF2 [4x96]@[96x64] ----------
    {
        const hfp* Rh = ldsh + L_R*2;
        h4x af[6];
        #pragma unroll
        for (int kt = 0; kt < 6; ++kt) af[kt] = *(const h4x*)(Rh + e16*L2STRH + kt*16 + g4);
        f4x yacc[4];
        #pragma unroll
        for (int tn = 0; tn < 4; ++tn) {
            yacc[tn] = (f4x){0.f,0.f,0.f,0.f};
            #pragma unroll
            for (int kt = 0; kt < 6; ++kt) {
                h4x bf = *(const h4x*)(wsh + OFF_L2*2 + (16*tn + e16)*L2STRH + kt*16 + g4);
                yacc[tn] = __builtin_amdgcn_mfma_f32_16x16x16f16(af[kt], bf, yacc[tn], 0, 0, 0);
            }
        }
        if (lane < 16) {
            #pragma unroll
            for (int tn = 0; tn < 4; ++tn) {
                const float bb = ws[OFF_SM + SM_B2 + tn*16 + lane];
                #pragma unroll
                for (int rr = 0; rr < 4; ++rr)
                    lds[L_PRE + rr*68 + tn*16 + lane] = yacc[tn][rr] + bb;
            }
        }
    }
    WAVE_SYNC();

    // ---------- phase 8: LN2 + residual(h1) + store ----------
    {
        const f4x ln2w4 = *(const f4x*)(ws + OFF_SM + SM_LN2W + c0);
        const f4x ln2b4 = *(const f4x*)(ws + OFF_SM + SM_LN2B + c0);
        const int m = lane >> 4;
        f4x pv = *(const f4x*)(lds + L_PRE + m*68 + c0);
        h4x h1p = *(const h4x*)((const hfp*)(lds + L_H1) + m*WOSTR + c0);
        f4x tot;
        tot.x = pv.x + (float)h1p.x;
        tot.y = pv.y + (float)h1p.y;
        tot.z = pv.z + (float)h1p.z;
        tot.w = pv.w + (float)h1p.w;
        float s = (tot.x + tot.y) + (tot.z + tot.w);
        float mu = rowsum16(s) * (1.f/64.f);
        f4x d; d.x = tot.x-mu; d.y = tot.y-mu; d.z = tot.z-mu; d.w = tot.w-mu;
        float v = (d.x*d.x + d.y*d.y) + (d.z*d.z + d.w*d.w);
        float rs = rsqrtf(rowsum16(v)*(1.f/64.f) + EPSF);
        f4x y;
        y.x = d.x*rs*ln2w4.x + ln2b4.x;
        y.y = d.y*rs*ln2w4.y + ln2b4.y;
        y.z = d.z*rs*ln2w4.z + ln2b4.z;
        y.w = d.w*rs*ln2w4.w + ln2b4.w;
        float* ob = out + ((size_t)b*1024 + kgo + k0 + m)*128;
        *(f4x*)(ob + c0)      = y;
        *(f4x*)(ob + 64 + c0) = y;   // tile (1,1,2)
    }
}

__global__ __launch_bounds__(64) void k_main(const float* __restrict__ x,
                                             const float* __restrict__ ws,
                                             float* __restrict__ out)
{
    __shared__ __align__(16) float lds[LDS_FLOATS];
    const int w = blockIdx.x;
    if (w < 256) {
        run4<72>(x, ws, lds, out, w >> 6, (w & 63)*4, 0, 256, 0);
    } else if (w < 512) {
        const int g = w - 256;
        run4<144>(x, ws, lds, out, g >> 6, (g & 63)*4, 18688, 256, 256);
    } else {
        const int g = w - 512;
        run4<144>(x, ws, lds, out, g >> 7, (g & 127)*4, 55808, 512, 512);
    }
}

extern "C" void kernel_launch(void* const* d_in, const int* in_sizes, int n_in,
                              void* d_out, int out_size, void* d_ws, size_t ws_size,
                              hipStream_t stream) {
    const float* x    = (const float*)d_in[0];
    const float* pe   = (const float*)d_in[1];
    const float* ct   = (const float*)d_in[2];
    const float* Wq   = (const float*)d_in[3];
    const float* bq   = (const float*)d_in[4];
    const float* Wo   = (const float*)d_in[5];
    const float* bo   = (const float*)d_in[6];
    const float* L1w  = (const float*)d_in[7];
    const float* b1   = (const float*)d_in[8];
    const float* L2w  = (const float*)d_in[9];
    const float* b2   = (const float*)d_in[10];
    const float* ln1w = (const float*)d_in[11];
    const float* ln1b = (const float*)d_in[12];
    const float* ln2w = (const float*)d_in[13];
    const float* ln2b = (const float*)d_in[14];
    float* out = (float*)d_out;
    float* ws  = (float*)d_ws;

    k_pre <<<150, 64, 0, stream>>>(pe, ct, Wq, bq, Wo, bo, L1w, b1, L2w, b2,
                                   ln1w, ln1b, ln2w, ln2b, ws);
    k_main<<<1024, 64, 0, stream>>>(x, ws, out);
}